// Round 1
// baseline (504.896 us; speedup 1.0000x reference)
//
#include <hip/hip_runtime.h>
#include <cstdint>
#include <cstddef>

// Match XLA: no FMA contraction anywhere in this TU (mul and add rounded separately).
#pragma clang fp contract(off)

#define N_PIX    524288     // 8*256*256 output pixels
#define CSPLANES 112        // 4*28 reduced planes
#define PLANE    65536      // 256*256
#define DCH      48         // max PRNG-loop depth (P(exceed) ~ 1e-30)

// ---------------- Threefry-2x32 (exact JAX semantics) ----------------
struct TF2 { uint32_t a, b; };

__host__ __device__ constexpr uint32_t rotl32(uint32_t x, int d) {
  return (x << d) | (x >> (32 - d));
}

__host__ __device__ constexpr TF2 threefry(uint32_t k0, uint32_t k1,
                                           uint32_t c0, uint32_t c1) {
  uint32_t ks2 = k0 ^ k1 ^ 0x1BD11BDAu;
  uint32_t x0 = c0 + k0;
  uint32_t x1 = c1 + k1;
  const int R0[4] = {13, 15, 26, 6};
  const int R1[4] = {17, 29, 16, 24};
  for (int i = 0; i < 4; ++i) { x0 += x1; x1 = rotl32(x1, R0[i]); x1 ^= x0; }
  x0 += k1;  x1 += ks2 + 1u;
  for (int i = 0; i < 4; ++i) { x0 += x1; x1 = rotl32(x1, R1[i]); x1 ^= x0; }
  x0 += ks2; x1 += k0 + 2u;
  for (int i = 0; i < 4; ++i) { x0 += x1; x1 = rotl32(x1, R0[i]); x1 ^= x0; }
  x0 += k0;  x1 += k1 + 3u;
  for (int i = 0; i < 4; ++i) { x0 += x1; x1 = rotl32(x1, R1[i]); x1 ^= x0; }
  x0 += k1;  x1 += ks2 + 4u;
  for (int i = 0; i < 4; ++i) { x0 += x1; x1 = rotl32(x1, R0[i]); x1 ^= x0; }
  x0 += ks2; x1 += k0 + 5u;
  return TF2{x0, x1};
}

// Key chains for the samplers, computed at COMPILE TIME (key = jax.random.key(1)).
// Convention: jax_threefry_partitionable = True (default since jax 0.4.36):
//   split(key, n)[i] = threefry(key, (0, i));  random_bits[j] = x0^x1 of threefry(key, (0, j))
struct Chains {
  uint32_t kg0, kg1;                                   // normal key
  uint32_t rj0a[DCH], rj0b[DCH], rj1a[DCH], rj1b[DCH]; // rejection split-3 chain from kp
  uint32_t kda[DCH], kdb[DCH];                         // knuth split-2 chain from kd
  uint32_t kpa[DCH], kpb[DCH];                         // knuth split-2 chain from kp (lam<10 fallback)
};

__host__ __device__ constexpr Chains make_chains() {
  Chains c{};
  TF2 kp = threefry(0u, 1u, 0u, 0u);   // split(key(1), 3) rows 0..2
  TF2 kd = threefry(0u, 1u, 0u, 1u);
  TF2 kg = threefry(0u, 1u, 0u, 2u);
  c.kg0 = kg.a; c.kg1 = kg.b;
  {
    uint32_t a = kp.a, b = kp.b;
    for (int i = 0; i < DCH; ++i) {
      TF2 nk = threefry(a, b, 0u, 0u);
      TF2 s0 = threefry(a, b, 0u, 1u);
      TF2 s1 = threefry(a, b, 0u, 2u);
      c.rj0a[i] = s0.a; c.rj0b[i] = s0.b;
      c.rj1a[i] = s1.a; c.rj1b[i] = s1.b;
      a = nk.a; b = nk.b;
    }
  }
  {
    uint32_t a = kd.a, b = kd.b;
    for (int i = 0; i < DCH; ++i) {
      TF2 nk = threefry(a, b, 0u, 0u);
      TF2 sk = threefry(a, b, 0u, 1u);
      c.kda[i] = sk.a; c.kdb[i] = sk.b;
      a = nk.a; b = nk.b;
    }
  }
  {
    uint32_t a = kp.a, b = kp.b;
    for (int i = 0; i < DCH; ++i) {
      TF2 nk = threefry(a, b, 0u, 0u);
      TF2 sk = threefry(a, b, 0u, 1u);
      c.kpa[i] = sk.a; c.kpb[i] = sk.b;
      a = nk.a; b = nk.b;
    }
  }
  return c;
}

__constant__ Chains G = make_chains();

// uniform [0,1) for flat element j under a given key (partitionable bit path)
__device__ inline float u01(uint32_t k0, uint32_t k1, uint32_t j) {
  TF2 r = threefry(k0, k1, 0u, j);
  uint32_t bits = r.a ^ r.b;
  return __uint_as_float((bits >> 9) | 0x3F800000u) - 1.0f;
}

// ---------------- XLA-exact special functions (f32, Lanczos / Giles) ----------------
__device__ inline float xla_lgamma(float x_in) {
  // no-reflection path only (argument k+1 >= 1 whenever the result matters)
  float z = x_in - 1.0f;
  float x = 1.0f;  // f32(kBaseLanczosCoeff)
  x = x + 676.520368121885098567009190444019f    / ((z + 0.0f) + 1.0f);
  x = x + (-1259.13921672240287047156078755283f) / ((z + 1.0f) + 1.0f);
  x = x + 771.3234287776530788486528258894f      / ((z + 2.0f) + 1.0f);
  x = x + (-176.61502916214059906584551354f)     / ((z + 3.0f) + 1.0f);
  x = x + 12.507343278686904814458936853f        / ((z + 4.0f) + 1.0f);
  x = x + (-0.13857109526572011689554707f)       / ((z + 5.0f) + 1.0f);
  x = x + 9.984369578019570859563e-6f            / ((z + 6.0f) + 1.0f);
  x = x + 1.50563273514931155834e-7f             / ((z + 7.0f) + 1.0f);
  float t = 7.5f + z;
  float log_t = 2.0149030205422647f + log1pf(z / 7.5f);
  return 0.91893853320467274178f + ((z + 0.5f) - t / log_t) * log_t + logf(x);
}

__device__ inline float xla_erfinv(float xx) {  // Giles 2012, as in XLA ErfInv32
  float w = -log1pf(-(xx * xx));
  float p;
  if (w < 5.0f) {
    float ww = w - 2.5f;
    p = 2.81022636e-08f;
    p = 3.43273939e-07f + p * ww;
    p = -3.5233877e-06f + p * ww;
    p = -4.39150654e-06f + p * ww;
    p = 0.00021858087f + p * ww;
    p = -0.00125372503f + p * ww;
    p = -0.00417768164f + p * ww;
    p = 0.246640727f + p * ww;
    p = 1.50140941f + p * ww;
  } else {
    float ww = sqrtf(w) - 3.0f;
    p = -0.000200214257f;
    p = 0.000100950558f + p * ww;
    p = 0.00134934322f + p * ww;
    p = -0.00367342844f + p * ww;
    p = 0.00573950773f + p * ww;
    p = -0.0076224613f + p * ww;
    p = 0.00943887047f + p * ww;
    p = 1.00167406f + p * ww;
    p = 2.83297682f + p * ww;
  }
  return p * xx;
}

__device__ inline float xla_normal(uint32_t j) {   // jax.random.normal(kg)[j]
  const float lo = -0.999999940395355224609375f;   // nextafter(-1, 0) in f32
  float f = u01(G.kg0, G.kg1, j);
  float u = f * (1.0f - lo) + lo;                  // (1-lo) folds to 2.0f, XLA-identical
  u = fmaxf(lo, u);
  return 1.41421356237309504880f * xla_erfinv(u);  // f32(np.sqrt(2))
}

// ---------------- JAX poisson samplers ----------------
__device__ inline int knuth_sample(const uint32_t* ka, const uint32_t* kb,
                                   uint32_t j, float lam) {
  const float neg = -lam;
  int k = 0;
  float lp = 0.0f;
  #pragma unroll 1
  for (int i = 0; i < DCH; ++i) {
    if (!(lp > neg)) break;
    ++k;
    float uu = u01(ka[i], kb[i], j);
    lp = lp + logf(uu);
  }
  return k - 1;
}

struct RejC { float lam, loglam, a, b, inva, vr; };

__device__ inline RejC make_rc(float lam) {
  RejC rc;
  rc.lam = lam;
  rc.loglam = logf(lam);
  rc.b = 0.931f + 2.53f * sqrtf(lam);
  rc.a = -0.059f + 0.02483f * rc.b;
  rc.inva = 1.1239f + 1.1328f / (rc.b - 3.4f);
  rc.vr = 0.9277f - 3.6224f / (rc.b - 2.0f);
  return rc;
}

// One body of jax's _poisson_rejection while-loop (iteration index i, 0-based)
__device__ inline bool rej_step(const RejC& rc, uint32_t j, int i, float* kout) {
  float u = u01(G.rj0a[i], G.rj0b[i], j) - 0.5f;
  float v = u01(G.rj1a[i], G.rj1b[i], j);
  float us = 0.5f - fabsf(u);
  float k = floorf(((2.0f * rc.a / us + rc.b) * u + rc.lam) + 0.43f);
  *kout = k;
  bool accept1 = (us >= 0.07f) && (v <= rc.vr);
  if (accept1) return true;
  bool reject = (k < 0.0f) || ((us < 0.013f) && (v > us));
  if (reject) return false;
  float s = logf(v * rc.inva / (rc.a / (us * us) + rc.b));
  float t = (-rc.lam + k * rc.loglam) - xla_lgamma(k + 1.0f);
  return s <= t;
}

// Per-pixel work shared by kernel 1 (single code copy to keep I$ small)
__device__ __noinline__ void process_pixel(uint32_t j, float cap,
                                           float& pk, float& dn, float& gn,
                                           unsigned& F) {
  float peak = cap + 1e-10f;
  pk = peak;
  dn = (float)knuth_sample(G.kda, G.kdb, j, 0.5f);   // Poisson(dark_t=0.5)
  gn = xla_normal(j) * 0.5f;                         // normal * gauss_t
  RejC rc = make_rc(peak);
  unsigned f = DCH;
  #pragma unroll 1
  for (int i = 0; i < DCH; ++i) {   // first-accept iteration (jax's global T input)
    float kc;
    if (rej_step(rc, j, i, &kc)) { f = (unsigned)(i + 1); break; }
  }
  F = f;
}

// ---------------- Kernel 1: reduction + peak/temps + global T ----------------
__global__ __launch_bounds__(128) void cap_kernel(const float* __restrict__ spec,
                                                  const float* __restrict__ filt,
                                                  float* __restrict__ out,
                                                  unsigned* __restrict__ tslot) {
  const int tid = blockIdx.x * 128 + threadIdx.x;   // 0..131071, 4 pixels each
  const int p = tid << 2;
  const int b = p >> 16;
  const int hw = p & 65535;
  const float* sp = spec + (size_t)b * ((size_t)CSPLANES * PLANE) + hw;
  const float* fp = filt + (size_t)b * ((size_t)CSPLANES * PLANE) + hw;
  float ax = 0.f, ay = 0.f, az = 0.f, aw = 0.f;
  #pragma unroll 4
  for (int cs = 0; cs < CSPLANES; ++cs) {
    const float4 s = *reinterpret_cast<const float4*>(sp + (size_t)cs * PLANE);
    const float4 f = *reinterpret_cast<const float4*>(fp + (size_t)cs * PLANE);
    ax += s.x * f.x; ay += s.y * f.y; az += s.z * f.z; aw += s.w * f.w;
  }

  float4 pk4, dn4, gn4;
  unsigned F0, F1, F2, F3;
  process_pixel((uint32_t)p + 0u, ax, pk4.x, dn4.x, gn4.x, F0);
  process_pixel((uint32_t)p + 1u, ay, pk4.y, dn4.y, gn4.y, F1);
  process_pixel((uint32_t)p + 2u, az, pk4.z, dn4.z, gn4.z, F2);
  process_pixel((uint32_t)p + 3u, aw, pk4.w, dn4.w, gn4.w, F3);

  reinterpret_cast<float4*>(out + N_PIX)[tid] = pk4;      // output 1: peak
  reinterpret_cast<float4*>(out)[tid] = dn4;              // temp: dnoisy
  reinterpret_cast<float4*>(out + 2 * N_PIX)[tid] = gn4;  // temp: gnoisy

  unsigned Fm0 = F0 > F1 ? F0 : F1;
  unsigned Fm1 = F2 > F3 ? F2 : F3;
  unsigned Fm = Fm0 > Fm1 ? Fm0 : Fm1;
  for (int off = 32; off; off >>= 1) {
    unsigned o = (unsigned)__shfl_down((int)Fm, off, 64);
    Fm = Fm > o ? Fm : o;
  }
  __shared__ unsigned sred[2];
  if ((threadIdx.x & 63) == 0) sred[threadIdx.x >> 6] = Fm;
  __syncthreads();
  if (threadIdx.x == 0) {
    unsigned m = sred[0] > sred[1] ? sred[0] : sred[1];
    atomicMax(tslot, m);
  }
}

// ---------------- Kernel 2: resolve pnoisy (last accept <= T) + final outputs ----------------
__global__ __launch_bounds__(256) void resolve_kernel(float* __restrict__ out,
                                                      const unsigned* __restrict__ tslot) {
  const uint32_t j = blockIdx.x * 256u + threadIdx.x;
  const int T = (int)(*tslot);
  const float peak = out[N_PIX + j];
  const float d = out[j];
  const float g = out[2 * N_PIX + j];
  float pv;
  if (peak >= 10.0f) {
    RejC rc = make_rc(peak);
    float kk = -1.0f;
    #pragma unroll 1
    for (int i = T - 1; i >= 0; --i) {   // downward scan: first hit = last accept <= T
      float kc;
      if (rej_step(rc, j, i, &kc)) { kk = kc; break; }
    }
    pv = (float)(int)kk;
  } else if (peak <= 0.0f) {
    pv = 0.0f;
  } else {
    pv = (float)knuth_sample(G.kpa, G.kpb, j, peak);
  }
  const float noisy = ((pv + d) + g) * 10.0f / 255.0f;
  out[j] = noisy;               // output 0
  out[2 * N_PIX + j] = 0.5f;    // output 2: dark_t
  out[3 * N_PIX + j] = 0.25f;   // output 3: gauss_t^2
}

extern "C" void kernel_launch(void* const* d_in, const int* in_sizes, int n_in,
                              void* d_out, int out_size, void* d_ws, size_t ws_size,
                              hipStream_t stream) {
  (void)in_sizes; (void)n_in; (void)out_size; (void)ws_size;
  const float* spec = (const float*)d_in[0];
  const float* filt = (const float*)d_in[1];
  float* out = (float*)d_out;
  unsigned* tslot = (unsigned*)d_ws;
  (void)hipMemsetAsync(d_ws, 0, sizeof(unsigned), stream);
  hipLaunchKernelGGL(cap_kernel, dim3(1024), dim3(128), 0, stream,
                     spec, filt, out, tslot);
  hipLaunchKernelGGL(resolve_kernel, dim3(2048), dim3(256), 0, stream,
                     out, tslot);
}